// Round 6
// baseline (1591.519 us; speedup 1.0000x reference)
//
#include <hip/hip_runtime.h>

#define NN 100000
#define EE 1600000
#define KITER 10

typedef __attribute__((ext_vector_type(8))) short s16x8;
typedef __attribute__((ext_vector_type(4))) float f32x4;

__device__ __forceinline__ short f2bf(float f) {
    union { float f; unsigned u; } v; v.f = f;
    unsigned r = v.u + 0x7FFFu + ((v.u >> 16) & 1u);   // RNE
    return (short)(r >> 16);
}

__device__ __forceinline__ void gload_lds16(const void* g, void* l) {
    __builtin_amdgcn_global_load_lds(
        (const __attribute__((address_space(1))) void*)g,
        (__attribute__((address_space(3))) void*)l, 16, 0, 0);
}

// ---------------------------------------------------------------------------
// bf16 MFMA GEMM: C = relu(A @ W^T + bias). Tile 128x128, 4 waves, 16x16x32.
// PROVEN round-3/5 kernel; only addition: PLANAR epilogue option that stores
// fp32 output in plane-major layout [col/8][row][col%8] for the propagation.
// ---------------------------------------------------------------------------
template<int KSTEPS, bool OUT_BF16, bool PLANAR>
__global__ __launch_bounds__(256)
void mfma_gemm(const short* __restrict__ A, int lda, const short* __restrict__ B,
               const float* __restrict__ bias, int nbias,
               void* __restrict__ Cout, int ldc, int ncols_store, int nrows)
{
    __shared__ short ldsA[128 * 32];
    __shared__ short ldsB[128 * 32];
    const int t    = threadIdx.x;
    const int lane = t & 63;
    const int wid  = t >> 6;
    const int rowBase = blockIdx.y * 128;
    const int colBase = blockIdx.x * 128;
    const int wrow = (wid >> 1) * 64;
    const int wcol = (wid & 1) * 64;

    const int q  = t & 3;    // 8-elem (16B) chunk within 32-wide k tile
    const int rl = t >> 2;   // 0..63

    f32x4 acc[4][4] = {};
    const int KPB = KSTEPS * 32;   // B row stride (padded)

    for (int ks = 0; ks < KSTEPS; ++ks) {
        const int k0 = ks * 32;

        #pragma unroll
        for (int i = 0; i < 2; ++i) {
            const short* srcB = B + (size_t)(colBase + rl + i * 64) * KPB + k0 + q * 8;
            gload_lds16(srcB, &ldsB[wid * 512 + i * 2048]);
        }
        #pragma unroll
        for (int i = 0; i < 2; ++i) {
            int grow = rowBase + rl + i * 64; if (grow > NN - 1) grow = NN - 1;
            const short* srcA = A + (size_t)grow * lda + k0 + q * 8;
            gload_lds16(srcA, &ldsA[wid * 512 + i * 2048]);
        }

        __syncthreads();

        {
            const int kb = lane >> 4;
            const int l16 = lane & 15;
            s16x8 a[4], b[4];
            #pragma unroll
            for (int m = 0; m < 4; ++m)
                a[m] = *(const s16x8*)&ldsA[(wrow + m * 16 + l16) * 32 + kb * 8];
            #pragma unroll
            for (int n = 0; n < 4; ++n)
                b[n] = *(const s16x8*)&ldsB[(wcol + n * 16 + l16) * 32 + kb * 8];
            #pragma unroll
            for (int m = 0; m < 4; ++m)
                #pragma unroll
                for (int n = 0; n < 4; ++n)
                    acc[m][n] = __builtin_amdgcn_mfma_f32_16x16x32_bf16(
                        a[m], b[n], acc[m][n], 0, 0, 0);
        }

        __syncthreads();
    }

    const int crow0 = (lane >> 4) * 4;
    const int ccol  = lane & 15;
    #pragma unroll
    for (int n = 0; n < 4; ++n) {
        int col = colBase + wcol + n * 16 + ccol;
        float bv = (col < nbias) ? bias[col] : 0.f;
        #pragma unroll
        for (int m = 0; m < 4; ++m) {
            #pragma unroll
            for (int j = 0; j < 4; ++j) {
                int row = rowBase + wrow + m * 16 + crow0 + j;
                if (row >= nrows) continue;
                float v = acc[m][n][j] + bv;
                v = fmaxf(v, 0.f);
                if (OUT_BF16) {
                    ((short*)Cout)[(size_t)row * ldc + col] = f2bf(v);
                } else if (col < ncols_store) {
                    if (PLANAR)
                        ((float*)Cout)[((size_t)(col >> 3) * NN + row) * 8 + (col & 7)] = v;
                    else
                        ((float*)Cout)[(size_t)row * ldc + col] = v;
                }
            }
        }
    }
}

// ---------------------------------------------------------------------------
// x fp32 [N][500] -> bf16 [N][500] contiguous, 8 elems/thread
// ---------------------------------------------------------------------------
__global__ void convert_x_kernel(const float* __restrict__ in, short* __restrict__ out) {
    int idx = blockIdx.x * blockDim.x + threadIdx.x;
    if (idx >= (NN * 500) / 8) return;
    const float4* in4 = (const float4*)in;
    float4 a = in4[(size_t)idx * 2];
    float4 b = in4[(size_t)idx * 2 + 1];
    s16x8 s;
    s[0]=f2bf(a.x); s[1]=f2bf(a.y); s[2]=f2bf(a.z); s[3]=f2bf(a.w);
    s[4]=f2bf(b.x); s[5]=f2bf(b.y); s[6]=f2bf(b.z); s[7]=f2bf(b.w);
    *(s16x8*)&out[(size_t)idx * 8] = s;
}

__global__ void convert_w_kernel(const float* __restrict__ in, short* __restrict__ out,
                                 int R, int C, int Rp, int Cp) {
    int idx = blockIdx.x * blockDim.x + threadIdx.x;
    if (idx >= Rp * Cp) return;
    int r = idx / Cp, c = idx - r * Cp;
    float v = (r < R && c < C) ? in[r * C + c] : 0.f;
    out[idx] = f2bf(v);
}

// ---------------------------------------------------------------------------
// Graph build: CSR-by-dst with packed (src, norm) pairs
// ---------------------------------------------------------------------------
__global__ void deg_init_kernel(int* deg, int n) {
    int i = blockIdx.x * blockDim.x + threadIdx.x;
    if (i < n) deg[i] = 1;
}
__global__ void deg_count_kernel(const int* __restrict__ dst, int* deg, int e) {
    int i = blockIdx.x * blockDim.x + threadIdx.x;
    if (i < e) atomicAdd(&deg[dst[i]], 1);
}
__global__ void dinv_kernel(const int* __restrict__ deg, float* __restrict__ dinv,
                            float* __restrict__ dinv2, int n) {
    int i = blockIdx.x * blockDim.x + threadIdx.x;
    if (i < n) {
        float d = (float)deg[i];
        dinv[i] = rsqrtf(d);
        dinv2[i] = 1.0f / d;
    }
}
__global__ __launch_bounds__(256)
void scan1_kernel(const int* __restrict__ deg, int* __restrict__ row_ptr,
                  int* __restrict__ blockSums, int n) {
    __shared__ int sdata[256];
    const int base = blockIdx.x * 2048;
    const int t = threadIdx.x;
    int local[8];
    int s = 0;
    #pragma unroll
    for (int i = 0; i < 8; ++i) {
        int idx = base + t * 8 + i;
        int c = (idx < n) ? (deg[idx] - 1) : 0;
        local[i] = s;
        s += c;
    }
    sdata[t] = s;
    __syncthreads();
    for (int off = 1; off < 256; off <<= 1) {
        int v = (t >= off) ? sdata[t - off] : 0;
        __syncthreads();
        sdata[t] += v;
        __syncthreads();
    }
    int excl = (t == 0) ? 0 : sdata[t - 1];
    #pragma unroll
    for (int i = 0; i < 8; ++i) {
        int idx = base + t * 8 + i;
        if (idx < n) row_ptr[idx] = excl + local[i];
    }
    if (t == 255) blockSums[blockIdx.x] = sdata[255];
}
__global__ void scan2_kernel(int* blockSums, int nb) {
    if (threadIdx.x == 0 && blockIdx.x == 0) {
        int s = 0;
        for (int i = 0; i < nb; ++i) { int v = blockSums[i]; blockSums[i] = s; s += v; }
    }
}
__global__ void scan3_kernel(int* __restrict__ row_ptr, int* __restrict__ cursor,
                             const int* __restrict__ blockSums, int n, int e) {
    int i = blockIdx.x * blockDim.x + threadIdx.x;
    if (i < n) {
        int v = row_ptr[i] + blockSums[i >> 11];
        row_ptr[i] = v;
        cursor[i] = v;
    }
    if (i == 0) row_ptr[n] = e;
}
__global__ void fill_csr_kernel(const int* __restrict__ src, const int* __restrict__ dst,
                                const float* __restrict__ dinv, int* cursor,
                                int2* __restrict__ pairs, int e) {
    int i = blockIdx.x * blockDim.x + threadIdx.x;
    if (i < e) {
        int s = src[i], d = dst[i];
        int pos = atomicAdd(&cursor[d], 1);
        float nv = dinv[s] * dinv[d];
        pairs[pos] = make_int2(s, __float_as_int(nv));
    }
}

// ---------------------------------------------------------------------------
// APPNP step, plane-sliced: h stored as 5 planes [plane][node][8 floats]
// (plane = 3.2 MB, fits per-XCD L2). One block = one plane x 256 dsts; the
// blockIdx%8 slot pins a plane's blocks to one XCD so gathers are L2-hits:
//   slots 3,4 -> planes 3,4 (all dst blocks)
//   slots 0,1,2 -> planes 0,1,2 even dst blocks; slots 5,6,7 -> odd.
// NB = 391 dst blocks of 256 dsts.
// ---------------------------------------------------------------------------
#define NB_DST 391
__global__ __launch_bounds__(256)
void prop_plane_kernel(const float4* __restrict__ hinP, const float4* __restrict__ h0P,
                       const int* __restrict__ rowp, const int2* __restrict__ pairs,
                       const float* __restrict__ dinv2, float4* __restrict__ houtP,
                       float* __restrict__ outFinal)
{
    const int s = blockIdx.x & 7;
    const int j = blockIdx.x >> 3;
    int plane, dstblk;
    if (s < 3)      { if (j >= 196) return; plane = s;     dstblk = 2 * j; }
    else if (s < 5) {                       plane = s;     dstblk = j; }
    else            { if (j >= 195) return; plane = s - 5; dstblk = 2 * j + 1; }
    const int dst = dstblk * 256 + threadIdx.x;
    if (dst >= NN) return;

    const float4* hp = hinP + (size_t)plane * NN * 2;   // plane base (float4 units)
    const size_t self = (size_t)dst * 2;

    float4 a0, a1;
    {
        const float dv = dinv2[dst];
        float4 s0 = hp[self], s1 = hp[self + 1];
        a0.x = dv * s0.x; a0.y = dv * s0.y; a0.z = dv * s0.z; a0.w = dv * s0.w;
        a1.x = dv * s1.x; a1.y = dv * s1.y; a1.z = dv * s1.z; a1.w = dv * s1.w;
    }

    int e = rowp[dst];
    const int e1 = rowp[dst + 1];

    for (; e + 4 <= e1; e += 4) {
        int2 p0 = pairs[e], p1 = pairs[e + 1], p2 = pairs[e + 2], p3 = pairs[e + 3];
        const size_t i0 = (size_t)p0.x * 2, i1 = (size_t)p1.x * 2;
        const size_t i2 = (size_t)p2.x * 2, i3 = (size_t)p3.x * 2;
        float4 g00 = hp[i0], g01 = hp[i0 + 1];
        float4 g10 = hp[i1], g11 = hp[i1 + 1];
        float4 g20 = hp[i2], g21 = hp[i2 + 1];
        float4 g30 = hp[i3], g31 = hp[i3 + 1];
        float w0 = __int_as_float(p0.y), w1 = __int_as_float(p1.y);
        float w2 = __int_as_float(p2.y), w3 = __int_as_float(p3.y);
        a0.x = fmaf(w0, g00.x, a0.x); a0.y = fmaf(w0, g00.y, a0.y);
        a0.z = fmaf(w0, g00.z, a0.z); a0.w = fmaf(w0, g00.w, a0.w);
        a1.x = fmaf(w0, g01.x, a1.x); a1.y = fmaf(w0, g01.y, a1.y);
        a1.z = fmaf(w0, g01.z, a1.z); a1.w = fmaf(w0, g01.w, a1.w);
        a0.x = fmaf(w1, g10.x, a0.x); a0.y = fmaf(w1, g10.y, a0.y);
        a0.z = fmaf(w1, g10.z, a0.z); a0.w = fmaf(w1, g10.w, a0.w);
        a1.x = fmaf(w1, g11.x, a1.x); a1.y = fmaf(w1, g11.y, a1.y);
        a1.z = fmaf(w1, g11.z, a1.z); a1.w = fmaf(w1, g11.w, a1.w);
        a0.x = fmaf(w2, g20.x, a0.x); a0.y = fmaf(w2, g20.y, a0.y);
        a0.z = fmaf(w2, g20.z, a0.z); a0.w = fmaf(w2, g20.w, a0.w);
        a1.x = fmaf(w2, g21.x, a1.x); a1.y = fmaf(w2, g21.y, a1.y);
        a1.z = fmaf(w2, g21.z, a1.z); a1.w = fmaf(w2, g21.w, a1.w);
        a0.x = fmaf(w3, g30.x, a0.x); a0.y = fmaf(w3, g30.y, a0.y);
        a0.z = fmaf(w3, g30.z, a0.z); a0.w = fmaf(w3, g30.w, a0.w);
        a1.x = fmaf(w3, g31.x, a1.x); a1.y = fmaf(w3, g31.y, a1.y);
        a1.z = fmaf(w3, g31.z, a1.z); a1.w = fmaf(w3, g31.w, a1.w);
    }
    for (; e < e1; ++e) {
        int2 p = pairs[e];
        const size_t i0 = (size_t)p.x * 2;
        float4 g0 = hp[i0], g1 = hp[i0 + 1];
        float w = __int_as_float(p.y);
        a0.x = fmaf(w, g0.x, a0.x); a0.y = fmaf(w, g0.y, a0.y);
        a0.z = fmaf(w, g0.z, a0.z); a0.w = fmaf(w, g0.w, a0.w);
        a1.x = fmaf(w, g1.x, a1.x); a1.y = fmaf(w, g1.y, a1.y);
        a1.z = fmaf(w, g1.z, a1.z); a1.w = fmaf(w, g1.w, a1.w);
    }

    const float4* h0p = h0P + (size_t)plane * NN * 2;
    float4 h00 = h0p[self], h01 = h0p[self + 1];
    float4 o0, o1;
    o0.x = fmaf(0.9f, a0.x, 0.1f * h00.x);
    o0.y = fmaf(0.9f, a0.y, 0.1f * h00.y);
    o0.z = fmaf(0.9f, a0.z, 0.1f * h00.z);
    o0.w = fmaf(0.9f, a0.w, 0.1f * h00.w);
    o1.x = fmaf(0.9f, a1.x, 0.1f * h01.x);
    o1.y = fmaf(0.9f, a1.y, 0.1f * h01.y);
    o1.z = fmaf(0.9f, a1.z, 0.1f * h01.z);
    o1.w = fmaf(0.9f, a1.w, 0.1f * h01.w);

    if (outFinal) {
        float4* op = (float4*)(outFinal + (size_t)dst * 40 + plane * 8);
        op[0] = o0; op[1] = o1;
    } else {
        float4* op = houtP + (size_t)plane * NN * 2 + self;
        op[0] = o0; op[1] = o1;
    }
}

// ---------------------------------------------------------------------------
extern "C" void kernel_launch(void* const* d_in, const int* in_sizes, int n_in,
                              void* d_out, int out_size, void* d_ws, size_t ws_size,
                              hipStream_t stream) {
    const float* x  = (const float*)d_in[0];
    const int* ei   = (const int*)d_in[1];
    const float* W0 = (const float*)d_in[2];
    const float* b0 = (const float*)d_in[3];
    const float* W1 = (const float*)d_in[4];
    const float* b1 = (const float*)d_in[5];
    const float* W2 = (const float*)d_in[6];
    const float* b2 = (const float*)d_in[7];
    float* out = (float*)d_out;
    char* ws = (char*)d_ws;

    const int* src = ei;
    const int* dst = ei + EE;

    // ---- Workspace layout (round-5 proven), total 151.6 MB ----
    short* xb   = (short*)(ws);                   // [N][500] bf16
    short* h1b  = (short*)(ws + 100000000);       // [N][256] bf16
    short* W0b  = (short*)(ws + 151200000);       // [256][512]
    short* W1b  = (short*)(ws + 151462144);       // [128][256]
    short* W2b  = (short*)(ws + 151527680);       // [128][128] (ends 151,560,448)

    short* h2b  = (short*)(ws);                   // [N][128] bf16 (reuse xb)
    float* h0   = (float*)(ws + 25600000);        // [5][N][8] f32 plane-major
    float* hA   = (float*)(ws + 41600000);        // [5][N][8]
    float* hB   = (float*)(ws + 57600000);        // [5][N][8] (ends 73.6e6)

    int2*  pairs= (int2*) (ws + 100000000);       // [E] (reuse h1b)
    int*   deg  = (int*)  (ws + 112800000);       // [N]
    float* dinv = (float*)(ws + 113200000);       // [N]
    float* dnv2 = (float*)(ws + 113600000);       // [N]
    int*   rowp = (int*)  (ws + 114000000);       // [N+1]
    int*   curs = (int*)  (ws + 114400008);       // [N]
    int*   bsum = (int*)  (ws + 114800008);       // [4096]
    (void)ws_size; (void)in_sizes; (void)n_in; (void)out_size;

    // ---- conversions ----
    convert_x_kernel<<<((NN * 500 / 8) + 255) / 256, 256, 0, stream>>>(x, xb);
    convert_w_kernel<<<(256 * 512 + 255) / 256, 256, 0, stream>>>(W0, W0b, 256, 500, 256, 512);
    convert_w_kernel<<<(128 * 256 + 255) / 256, 256, 0, stream>>>(W1, W1b, 128, 256, 128, 256);
    convert_w_kernel<<<(128 * 128 + 255) / 256, 256, 0, stream>>>(W2, W2b, 40, 128, 128, 128);

    // ---- MLP encoder ----
    const int NBLK = (NN + 127) / 128;  // 782
    mfma_gemm<16, true,  false><<<dim3(2, NBLK), 256, 0, stream>>>(
        xb, 500, W0b, b0, 256, (void*)h1b, 256, 256, NN);
    mfma_gemm<8,  true,  false><<<dim3(1, NBLK), 256, 0, stream>>>(
        h1b, 256, W1b, b1, 128, (void*)h2b, 128, 128, NN);
    mfma_gemm<4,  false, true ><<<dim3(1, NBLK), 256, 0, stream>>>(
        h2b, 128, W2b, b2, 40, (void*)h0, 40, 40, NN);   // plane-major h0

    // ---- graph build (after GEMM1: h1b region is dead) ----
    {
        int nb_n = (NN + 255) / 256;
        int nb_e = (EE + 255) / 256;
        deg_init_kernel<<<nb_n, 256, 0, stream>>>(deg, NN);
        deg_count_kernel<<<nb_e, 256, 0, stream>>>(dst, deg, EE);
        dinv_kernel<<<nb_n, 256, 0, stream>>>(deg, dinv, dnv2, NN);
        int nb_scan = (NN + 2047) / 2048;
        scan1_kernel<<<nb_scan, 256, 0, stream>>>(deg, rowp, bsum, NN);
        scan2_kernel<<<1, 64, 0, stream>>>(bsum, nb_scan);
        scan3_kernel<<<nb_n, 256, 0, stream>>>(rowp, curs, bsum, NN, EE);
        fill_csr_kernel<<<nb_e, 256, 0, stream>>>(src, dst, dinv, curs, pairs, EE);
    }

    // ---- APPNP propagation (plane-sliced, XCD-pinned) ----
    {
        dim3 blk(256);
        dim3 grd(8 * NB_DST);   // 3128 (some slots early-exit)
        const float* hin = h0;
        for (int it = 0; it < KITER; ++it) {
            float* houtP = (it & 1) ? hB : hA;
            float* fin   = (it == KITER - 1) ? out : nullptr;
            prop_plane_kernel<<<grd, blk, 0, stream>>>(
                (const float4*)hin, (const float4*)h0, rowp, pairs, dnv2,
                (float4*)houtP, fin);
            hin = houtP;
        }
    }
}

// Round 7
// 756.470 us; speedup vs baseline: 2.1039x; 2.1039x over previous
//
#include <hip/hip_runtime.h>

#define NN 100000
#define EE 1600000
#define KITER 10

typedef __attribute__((ext_vector_type(8))) short s16x8;
typedef __attribute__((ext_vector_type(4))) float f32x4;

__device__ __forceinline__ short f2bf(float f) {
    union { float f; unsigned u; } v; v.f = f;
    unsigned r = v.u + 0x7FFFu + ((v.u >> 16) & 1u);   // RNE
    return (short)(r >> 16);
}
__device__ __forceinline__ float bf2f(short s) {
    return __uint_as_float((unsigned)(unsigned short)s << 16);
}

__device__ __forceinline__ void gload_lds16(const void* g, void* l) {
    __builtin_amdgcn_global_load_lds(
        (const __attribute__((address_space(1))) void*)g,
        (__attribute__((address_space(3))) void*)l, 16, 0, 0);
}

// ---------------------------------------------------------------------------
// bf16 MFMA GEMM: C = relu(A @ W^T + bias). Tile 128x128, 4 waves, 16x16x32.
// PROVEN round-3/5 kernel. Changes: (1) bf16-output path now masks
// col < ncols_store (needed for ldc=40); (2) optional second fp32 output C2.
// ---------------------------------------------------------------------------
template<int KSTEPS, bool OUT_BF16>
__global__ __launch_bounds__(256)
void mfma_gemm(const short* __restrict__ A, int lda, const short* __restrict__ B,
               const float* __restrict__ bias, int nbias,
               void* __restrict__ Cout, int ldc, int ncols_store, int nrows,
               float* __restrict__ C2)
{
    __shared__ short ldsA[128 * 32];
    __shared__ short ldsB[128 * 32];
    const int t    = threadIdx.x;
    const int lane = t & 63;
    const int wid  = t >> 6;
    const int rowBase = blockIdx.y * 128;
    const int colBase = blockIdx.x * 128;
    const int wrow = (wid >> 1) * 64;
    const int wcol = (wid & 1) * 64;

    const int q  = t & 3;    // 8-elem (16B) chunk within 32-wide k tile
    const int rl = t >> 2;   // 0..63

    f32x4 acc[4][4] = {};
    const int KPB = KSTEPS * 32;   // B row stride (padded)

    for (int ks = 0; ks < KSTEPS; ++ks) {
        const int k0 = ks * 32;

        #pragma unroll
        for (int i = 0; i < 2; ++i) {
            const short* srcB = B + (size_t)(colBase + rl + i * 64) * KPB + k0 + q * 8;
            gload_lds16(srcB, &ldsB[wid * 512 + i * 2048]);
        }
        #pragma unroll
        for (int i = 0; i < 2; ++i) {
            int grow = rowBase + rl + i * 64; if (grow > NN - 1) grow = NN - 1;
            const short* srcA = A + (size_t)grow * lda + k0 + q * 8;
            gload_lds16(srcA, &ldsA[wid * 512 + i * 2048]);
        }

        __syncthreads();

        {
            const int kb = lane >> 4;
            const int l16 = lane & 15;
            s16x8 a[4], b[4];
            #pragma unroll
            for (int m = 0; m < 4; ++m)
                a[m] = *(const s16x8*)&ldsA[(wrow + m * 16 + l16) * 32 + kb * 8];
            #pragma unroll
            for (int n = 0; n < 4; ++n)
                b[n] = *(const s16x8*)&ldsB[(wcol + n * 16 + l16) * 32 + kb * 8];
            #pragma unroll
            for (int m = 0; m < 4; ++m)
                #pragma unroll
                for (int n = 0; n < 4; ++n)
                    acc[m][n] = __builtin_amdgcn_mfma_f32_16x16x32_bf16(
                        a[m], b[n], acc[m][n], 0, 0, 0);
        }

        __syncthreads();
    }

    const int crow0 = (lane >> 4) * 4;
    const int ccol  = lane & 15;
    #pragma unroll
    for (int n = 0; n < 4; ++n) {
        int col = colBase + wcol + n * 16 + ccol;
        float bv = (col < nbias) ? bias[col] : 0.f;
        #pragma unroll
        for (int m = 0; m < 4; ++m) {
            #pragma unroll
            for (int j = 0; j < 4; ++j) {
                int row = rowBase + wrow + m * 16 + crow0 + j;
                if (row >= nrows) continue;
                float v = acc[m][n][j] + bv;
                v = fmaxf(v, 0.f);
                if (col < ncols_store) {
                    if (OUT_BF16)
                        ((short*)Cout)[(size_t)row * ldc + col] = f2bf(v);
                    else
                        ((float*)Cout)[(size_t)row * ldc + col] = v;
                    if (C2) C2[(size_t)row * ldc + col] = v;
                }
            }
        }
    }
}

// ---------------------------------------------------------------------------
// x fp32 [N][500] -> bf16 [N][500] contiguous, 8 elems/thread
// ---------------------------------------------------------------------------
__global__ void convert_x_kernel(const float* __restrict__ in, short* __restrict__ out) {
    int idx = blockIdx.x * blockDim.x + threadIdx.x;
    if (idx >= (NN * 500) / 8) return;
    const float4* in4 = (const float4*)in;
    float4 a = in4[(size_t)idx * 2];
    float4 b = in4[(size_t)idx * 2 + 1];
    s16x8 s;
    s[0]=f2bf(a.x); s[1]=f2bf(a.y); s[2]=f2bf(a.z); s[3]=f2bf(a.w);
    s[4]=f2bf(b.x); s[5]=f2bf(b.y); s[6]=f2bf(b.z); s[7]=f2bf(b.w);
    *(s16x8*)&out[(size_t)idx * 8] = s;
}

__global__ void convert_w_kernel(const float* __restrict__ in, short* __restrict__ out,
                                 int R, int C, int Rp, int Cp) {
    int idx = blockIdx.x * blockDim.x + threadIdx.x;
    if (idx >= Rp * Cp) return;
    int r = idx / Cp, c = idx - r * Cp;
    float v = (r < R && c < C) ? in[r * C + c] : 0.f;
    out[idx] = f2bf(v);
}

// ---------------------------------------------------------------------------
// Graph build: CSR-by-dst with packed (src, norm) pairs
// ---------------------------------------------------------------------------
__global__ void deg_init_kernel(int* deg, int n) {
    int i = blockIdx.x * blockDim.x + threadIdx.x;
    if (i < n) deg[i] = 1;
}
__global__ void deg_count_kernel(const int* __restrict__ dst, int* deg, int e) {
    int i = blockIdx.x * blockDim.x + threadIdx.x;
    if (i < e) atomicAdd(&deg[dst[i]], 1);
}
__global__ void dinv_kernel(const int* __restrict__ deg, float* __restrict__ dinv,
                            float* __restrict__ dinv2, int n) {
    int i = blockIdx.x * blockDim.x + threadIdx.x;
    if (i < n) {
        float d = (float)deg[i];
        dinv[i] = rsqrtf(d);
        dinv2[i] = 1.0f / d;
    }
}
__global__ __launch_bounds__(256)
void scan1_kernel(const int* __restrict__ deg, int* __restrict__ row_ptr,
                  int* __restrict__ blockSums, int n) {
    __shared__ int sdata[256];
    const int base = blockIdx.x * 2048;
    const int t = threadIdx.x;
    int local[8];
    int s = 0;
    #pragma unroll
    for (int i = 0; i < 8; ++i) {
        int idx = base + t * 8 + i;
        int c = (idx < n) ? (deg[idx] - 1) : 0;
        local[i] = s;
        s += c;
    }
    sdata[t] = s;
    __syncthreads();
    for (int off = 1; off < 256; off <<= 1) {
        int v = (t >= off) ? sdata[t - off] : 0;
        __syncthreads();
        sdata[t] += v;
        __syncthreads();
    }
    int excl = (t == 0) ? 0 : sdata[t - 1];
    #pragma unroll
    for (int i = 0; i < 8; ++i) {
        int idx = base + t * 8 + i;
        if (idx < n) row_ptr[idx] = excl + local[i];
    }
    if (t == 255) blockSums[blockIdx.x] = sdata[255];
}
__global__ void scan2_kernel(int* blockSums, int nb) {
    if (threadIdx.x == 0 && blockIdx.x == 0) {
        int s = 0;
        for (int i = 0; i < nb; ++i) { int v = blockSums[i]; blockSums[i] = s; s += v; }
    }
}
__global__ void scan3_kernel(int* __restrict__ row_ptr, int* __restrict__ cursor,
                             const int* __restrict__ blockSums, int n, int e) {
    int i = blockIdx.x * blockDim.x + threadIdx.x;
    if (i < n) {
        int v = row_ptr[i] + blockSums[i >> 11];
        row_ptr[i] = v;
        cursor[i] = v;
    }
    if (i == 0) row_ptr[n] = e;
}
__global__ void fill_csr_kernel(const int* __restrict__ src, const int* __restrict__ dst,
                                const float* __restrict__ dinv, int* cursor,
                                int2* __restrict__ pairs, int e) {
    int i = blockIdx.x * blockDim.x + threadIdx.x;
    if (i < e) {
        int s = src[i], d = dst[i];
        int pos = atomicAdd(&cursor[d], 1);
        float nv = dinv[s] * dinv[d];
        pairs[pos] = make_int2(s, __float_as_int(nv));
    }
}

// ---------------------------------------------------------------------------
// APPNP step, bf16 state: h stored [N][40] bf16 (80B rows = exactly 2 cache
// lines). 5 threads/node x 16B (8 bf16 feats each), 64 nodes per 320-thr block.
// fp32 accumulate; teleport term reads fp32 h0f (no extra rounding there).
// x8 unroll = 8 independent gathers in flight (round-5 proven pattern).
// ---------------------------------------------------------------------------
__global__ __launch_bounds__(320)
void prop_bf16_kernel(const short* __restrict__ hin, const float* __restrict__ h0f,
                      const int* __restrict__ rowp, const int2* __restrict__ pairs,
                      const float* __restrict__ dinv2,
                      short* __restrict__ hout, float* __restrict__ outF, int n)
{
    const int t = threadIdx.x;
    const int vl = t / 5;
    const int f = t - vl * 5;              // 0..4 -> features [f*8, f*8+8)
    const int v = blockIdx.x * 64 + vl;
    if (v >= n) return;

    float acc[8];
    {
        const float dv = dinv2[v];
        s16x8 s = *(const s16x8*)(hin + (size_t)v * 40 + f * 8);
        #pragma unroll
        for (int j = 0; j < 8; ++j) acc[j] = dv * bf2f(s[j]);
    }

    int e = rowp[v];
    const int e1 = rowp[v + 1];

    for (; e + 8 <= e1; e += 8) {
        int2 p0 = pairs[e],     p1 = pairs[e + 1], p2 = pairs[e + 2], p3 = pairs[e + 3];
        int2 p4 = pairs[e + 4], p5 = pairs[e + 5], p6 = pairs[e + 6], p7 = pairs[e + 7];
        s16x8 g0 = *(const s16x8*)(hin + (size_t)p0.x * 40 + f * 8);
        s16x8 g1 = *(const s16x8*)(hin + (size_t)p1.x * 40 + f * 8);
        s16x8 g2 = *(const s16x8*)(hin + (size_t)p2.x * 40 + f * 8);
        s16x8 g3 = *(const s16x8*)(hin + (size_t)p3.x * 40 + f * 8);
        s16x8 g4 = *(const s16x8*)(hin + (size_t)p4.x * 40 + f * 8);
        s16x8 g5 = *(const s16x8*)(hin + (size_t)p5.x * 40 + f * 8);
        s16x8 g6 = *(const s16x8*)(hin + (size_t)p6.x * 40 + f * 8);
        s16x8 g7 = *(const s16x8*)(hin + (size_t)p7.x * 40 + f * 8);
        float w0 = __int_as_float(p0.y), w1 = __int_as_float(p1.y);
        float w2 = __int_as_float(p2.y), w3 = __int_as_float(p3.y);
        float w4 = __int_as_float(p4.y), w5 = __int_as_float(p5.y);
        float w6 = __int_as_float(p6.y), w7 = __int_as_float(p7.y);
        #pragma unroll
        for (int j = 0; j < 8; ++j) acc[j] = fmaf(w0, bf2f(g0[j]), acc[j]);
        #pragma unroll
        for (int j = 0; j < 8; ++j) acc[j] = fmaf(w1, bf2f(g1[j]), acc[j]);
        #pragma unroll
        for (int j = 0; j < 8; ++j) acc[j] = fmaf(w2, bf2f(g2[j]), acc[j]);
        #pragma unroll
        for (int j = 0; j < 8; ++j) acc[j] = fmaf(w3, bf2f(g3[j]), acc[j]);
        #pragma unroll
        for (int j = 0; j < 8; ++j) acc[j] = fmaf(w4, bf2f(g4[j]), acc[j]);
        #pragma unroll
        for (int j = 0; j < 8; ++j) acc[j] = fmaf(w5, bf2f(g5[j]), acc[j]);
        #pragma unroll
        for (int j = 0; j < 8; ++j) acc[j] = fmaf(w6, bf2f(g6[j]), acc[j]);
        #pragma unroll
        for (int j = 0; j < 8; ++j) acc[j] = fmaf(w7, bf2f(g7[j]), acc[j]);
    }
    for (; e < e1; ++e) {
        int2 p = pairs[e];
        s16x8 g = *(const s16x8*)(hin + (size_t)p.x * 40 + f * 8);
        float w = __int_as_float(p.y);
        #pragma unroll
        for (int j = 0; j < 8; ++j) acc[j] = fmaf(w, bf2f(g[j]), acc[j]);
    }

    const float* h0p = h0f + (size_t)v * 40 + f * 8;
    float o[8];
    #pragma unroll
    for (int j = 0; j < 8; ++j) o[j] = fmaf(0.9f, acc[j], 0.1f * h0p[j]);

    if (outF) {
        float4* op = (float4*)(outF + (size_t)v * 40 + f * 8);
        op[0] = make_float4(o[0], o[1], o[2], o[3]);
        op[1] = make_float4(o[4], o[5], o[6], o[7]);
    } else {
        s16x8 s;
        #pragma unroll
        for (int j = 0; j < 8; ++j) s[j] = f2bf(o[j]);
        *(s16x8*)(hout + (size_t)v * 40 + f * 8) = s;
    }
}

// ---------------------------------------------------------------------------
extern "C" void kernel_launch(void* const* d_in, const int* in_sizes, int n_in,
                              void* d_out, int out_size, void* d_ws, size_t ws_size,
                              hipStream_t stream) {
    const float* x  = (const float*)d_in[0];
    const int* ei   = (const int*)d_in[1];
    const float* W0 = (const float*)d_in[2];
    const float* b0 = (const float*)d_in[3];
    const float* W1 = (const float*)d_in[4];
    const float* b1 = (const float*)d_in[5];
    const float* W2 = (const float*)d_in[6];
    const float* b2 = (const float*)d_in[7];
    float* out = (float*)d_out;
    char* ws = (char*)d_ws;

    const int* src = ei;
    const int* dst = ei + EE;

    // ---- Workspace layout (round-5 proven scheme), total 151.6 MB ----
    // Phase 1 (MLP): xb [0,100e6) ; h1b [100e6,151.2e6) ; weights at 151.2e6
    // Phase 2 (after GEMM0, region 0 reused): h2b, h0b, h0f, hA, hB
    // Phase 3 (after GEMM1, region 100e6 reused): pairs + graph arrays
    short* xb   = (short*)(ws);                   // [N][500] bf16
    short* h1b  = (short*)(ws + 100000000);       // [N][256] bf16
    short* W0b  = (short*)(ws + 151200000);       // [256][512]
    short* W1b  = (short*)(ws + 151462144);       // [128][256]
    short* W2b  = (short*)(ws + 151527680);       // [128][128] (ends 151,560,448)

    short* h2b  = (short*)(ws);                   // [N][128] bf16 (reuse xb)
    short* h0b  = (short*)(ws + 25600000);        // [N][40] bf16  ->  33.6e6
    float* h0f  = (float*)(ws + 33600000);        // [N][40] f32   ->  49.6e6
    short* hA   = (short*)(ws + 49600000);        // [N][40] bf16  ->  57.6e6
    short* hB   = (short*)(ws + 57600000);        // [N][40] bf16  ->  65.6e6

    int2*  pairs= (int2*) (ws + 100000000);       // [E] (reuse h1b)
    int*   deg  = (int*)  (ws + 112800000);       // [N]
    float* dinv = (float*)(ws + 113200000);       // [N]
    float* dnv2 = (float*)(ws + 113600000);       // [N]
    int*   rowp = (int*)  (ws + 114000000);       // [N+1]
    int*   curs = (int*)  (ws + 114400008);       // [N]
    int*   bsum = (int*)  (ws + 114800008);       // [4096]
    (void)ws_size; (void)in_sizes; (void)n_in; (void)out_size;

    // ---- conversions ----
    convert_x_kernel<<<((NN * 500 / 8) + 255) / 256, 256, 0, stream>>>(x, xb);
    convert_w_kernel<<<(256 * 512 + 255) / 256, 256, 0, stream>>>(W0, W0b, 256, 500, 256, 512);
    convert_w_kernel<<<(128 * 256 + 255) / 256, 256, 0, stream>>>(W1, W1b, 128, 256, 128, 256);
    convert_w_kernel<<<(128 * 128 + 255) / 256, 256, 0, stream>>>(W2, W2b, 40, 128, 128, 128);

    // ---- MLP encoder ----
    const int NBLK = (NN + 127) / 128;  // 782
    mfma_gemm<16, true ><<<dim3(2, NBLK), 256, 0, stream>>>(
        xb, 500, W0b, b0, 256, (void*)h1b, 256, 256, NN, nullptr);
    mfma_gemm<8,  true ><<<dim3(1, NBLK), 256, 0, stream>>>(
        h1b, 256, W1b, b1, 128, (void*)h2b, 128, 128, NN, nullptr);
    mfma_gemm<4,  true ><<<dim3(1, NBLK), 256, 0, stream>>>(
        h2b, 128, W2b, b2, 40, (void*)h0b, 40, 40, NN, h0f);  // bf16 + fp32 h0

    // ---- graph build (after GEMM1: h1b region is dead) ----
    {
        int nb_n = (NN + 255) / 256;
        int nb_e = (EE + 255) / 256;
        deg_init_kernel<<<nb_n, 256, 0, stream>>>(deg, NN);
        deg_count_kernel<<<nb_e, 256, 0, stream>>>(dst, deg, EE);
        dinv_kernel<<<nb_n, 256, 0, stream>>>(deg, dinv, dnv2, NN);
        int nb_scan = (NN + 2047) / 2048;
        scan1_kernel<<<nb_scan, 256, 0, stream>>>(deg, rowp, bsum, NN);
        scan2_kernel<<<1, 64, 0, stream>>>(bsum, nb_scan);
        scan3_kernel<<<nb_n, 256, 0, stream>>>(rowp, curs, bsum, NN, EE);
        fill_csr_kernel<<<nb_e, 256, 0, stream>>>(src, dst, dinv, curs, pairs, EE);
    }

    // ---- APPNP propagation (bf16 state) ----
    {
        dim3 blk(320);
        dim3 grd((NN + 63) / 64);  // 1563
        const short* hin = h0b;
        for (int it = 0; it < KITER; ++it) {
            short* hout = (it & 1) ? hB : hA;
            float* fin  = (it == KITER - 1) ? out : nullptr;
            prop_bf16_kernel<<<grd, blk, 0, stream>>>(
                hin, h0f, rowp, pairs, dnv2, hout, fin, NN);
            hin = hout;
        }
    }
}